// Round 8
// baseline (422.644 us; speedup 1.0000x reference)
//
#include <hip/hip_runtime.h>
#include <hip/hip_fp16.h>

#define N_NODES 50000
#define N_EDGES 500000
#define DIM 64
#define KDIM 4
#define HID 64
#define NCLS 40
#define NBLK ((N_NODES + 255) / 256)   // 196
#define EBLK ((N_EDGES + 255) / 256)   // 1954
#define TBLK ((N_NODES + 31) / 32)     // 1563 transform blocks

typedef unsigned uv4 __attribute__((ext_vector_type(4)));

__device__ inline unsigned pack2(float a, float b) {
    __half2 h = __floats2half2_rn(a, b);
    return *(unsigned*)&h;
}
__device__ inline float2 unpack2(unsigned u) {
    __half2 h = *(__half2*)&u;
    return __half22float2(h);
}
__device__ inline uint4 ldnt4(const uint4* p) {
    uv4 v = __builtin_nontemporal_load((const uv4*)p);
    return make_uint4(v.x, v.y, v.z, v.w);
}
__device__ inline void stnt4(uint4* p, uint4 v) {
    uv4 w = {v.x, v.y, v.z, v.w};
    __builtin_nontemporal_store(w, (uv4*)p);
}

// ---- histogram of dst (in-degree) ----
__global__ void hist_k(const int* __restrict__ dst, int* __restrict__ cnt) {
    int e = blockIdx.x * 256 + threadIdx.x;
    if (e < N_EDGES) atomicAdd(&cnt[dst[e]], 1);
}

// ---- single-kernel scan: per-block scan + publish + parallel lookback ----
__global__ __launch_bounds__(256) void scan_k(const int* __restrict__ cnt,
                                              int* __restrict__ start,
                                              int* __restrict__ cursor,
                                              volatile int* __restrict__ bflag,
                                              volatile int* __restrict__ bval) {
    __shared__ int ls[256];
    __shared__ int sbase;
    __shared__ int ok_all;
    int b = blockIdx.x, t = threadIdx.x;
    int n = b * 256 + t;
    int v = (n < N_NODES) ? cnt[n] : 0;
    ls[t] = v;
    __syncthreads();
#pragma unroll
    for (int off = 1; off < 256; off <<= 1) {
        int u = (t >= off) ? ls[t - off] : 0;
        __syncthreads();
        ls[t] += u;
        __syncthreads();
    }
    int incl = ls[t];
    int total = ls[255];
    __syncthreads();

    if (t == 0) {
        bval[b] = total;
        __threadfence();
        bflag[b] = 1;
    }

    if (b > 0) {
        for (;;) {
            int f = (t < b) ? bflag[t] : 1;
            if (t == 0) ok_all = 1;
            __syncthreads();
            if (!f) ok_all = 0;
            __syncthreads();
            if (ok_all) break;
        }
        __threadfence();
        int pv = (t < b) ? bval[t] : 0;
        ls[t] = pv;
        __syncthreads();
#pragma unroll
        for (int off = 128; off > 0; off >>= 1) {
            if (t < off) ls[t] += ls[t + off];
            __syncthreads();
        }
        if (t == 0) sbase = ls[0];
        __syncthreads();
    } else {
        if (t == 0) sbase = 0;
        __syncthreads();
    }

    int excl = sbase + incl - v;
    if (n < N_NODES) { start[n] = excl; cursor[n] = excl; }
    if (n == 0) start[N_NODES] = N_EDGES;
}

// ---- counting-sort scatter: write recA only; edge idx in .w for repack ----
__global__ void scatter_k(const int* __restrict__ src, const int* __restrict__ dst,
                          const float* __restrict__ ef, int* __restrict__ cursor,
                          uint4* __restrict__ recA) {
    int e = blockIdx.x * 256 + threadIdx.x;
    if (e < N_EDGES) {
        int d = dst[e];
        int pos = atomicAdd(&cursor[d], 1);
        int sn = src[e];
        float4 f0 = ((const float4*)ef)[e];
        stnt4(&recA[pos], make_uint4((unsigned)sn, pack2(f0.x, f0.y), pack2(f0.z, f0.w), (unsigned)e));
    }
}

// ---- streaming repack: build layer-1 records from recA order ----
__global__ void repack_k(const uint4* __restrict__ recA, const float* __restrict__ ef1,
                         uint4* __restrict__ recB) {
    int i = blockIdx.x * 256 + threadIdx.x;
    if (i < N_EDGES) {
        uint4 r = ldnt4(&recA[i]);
        int e = (int)r.w;
        float4 f1 = ((const float4*)ef1)[e];
        stnt4(&recB[i], make_uint4(r.x, pack2(f1.x, f1.y), pack2(f1.z, f1.w), 0u));
    }
}

// ---- node transform: 32 nodes/block, ALL 4 k per thread, sharded y layout ----
// y row (256 halves) = [jg(4)][jj(16)][k(4)]  -> half idx = jg*64 + jj*4 + k
// thread: 1 node (nl=t&31) x 8 cols (cg=t>>5 -> j0=cg*8) x 4 k  = 32 accs
// LDS: 32KB sW (k-pair slice, staged twice) + 8.3KB sh
__global__ __launch_bounds__(256) void transform_k(const float* __restrict__ hin,
                                                   const float* __restrict__ W,
                                                   unsigned* __restrict__ y) {
    __shared__ float sW[2 * 64 * 64];      // 32 KB
    __shared__ float sh[32 * 65];          // 8.3 KB
    int t = threadIdx.x;
    int n0 = blockIdx.x * 32;

    // stage h tile: 32 nodes x 16 float4 = 512 float4 -> 2 per thread
#pragma unroll
    for (int i = 0; i < 2; ++i) {
        int idx = t + 256 * i;        // 0..511
        int nl = idx >> 4;            // 0..31
        int dg = idx & 15;
        int n = n0 + nl;
        float4 v = make_float4(0.f, 0.f, 0.f, 0.f);
        if (n < N_NODES) v = ((const float4*)hin)[(size_t)n * 16 + dg];
        sh[nl * 65 + dg * 4 + 0] = v.x;
        sh[nl * 65 + dg * 4 + 1] = v.y;
        sh[nl * 65 + dg * 4 + 2] = v.z;
        sh[nl * 65 + dg * 4 + 3] = v.w;
    }

    int nl = t & 31;
    int cg = t >> 5;                  // 0..7
    int j0 = cg * 8;

    float accA[8][2];   // kpair 0: k=0,1
    float accB[8][2];   // kpair 1: k=2,3
#pragma unroll
    for (int c = 0; c < 8; ++c) { accA[c][0] = 0.f; accA[c][1] = 0.f;
                                  accB[c][0] = 0.f; accB[c][1] = 0.f; }

    // ---- k-pair 0 ----
    {
        const float4* W4 = (const float4*)W;   // k0,k1 slices (8192 floats)
        float4* sW4 = (float4*)sW;
#pragma unroll
        for (int i = 0; i < 8; ++i) sW4[t + 256 * i] = W4[t + 256 * i];
        __syncthreads();
        for (int d = 0; d < 64; ++d) {
            float a = sh[nl * 65 + d];
            const float4* w0 = (const float4*)&sW[d * 64 + j0];
            const float4* w1 = (const float4*)&sW[4096 + d * 64 + j0];
            float4 wa0 = w0[0], wb0 = w0[1];
            float4 wa1 = w1[0], wb1 = w1[1];
            accA[0][0] = fmaf(a, wa0.x, accA[0][0]); accA[0][1] = fmaf(a, wa1.x, accA[0][1]);
            accA[1][0] = fmaf(a, wa0.y, accA[1][0]); accA[1][1] = fmaf(a, wa1.y, accA[1][1]);
            accA[2][0] = fmaf(a, wa0.z, accA[2][0]); accA[2][1] = fmaf(a, wa1.z, accA[2][1]);
            accA[3][0] = fmaf(a, wa0.w, accA[3][0]); accA[3][1] = fmaf(a, wa1.w, accA[3][1]);
            accA[4][0] = fmaf(a, wb0.x, accA[4][0]); accA[4][1] = fmaf(a, wb1.x, accA[4][1]);
            accA[5][0] = fmaf(a, wb0.y, accA[5][0]); accA[5][1] = fmaf(a, wb1.y, accA[5][1]);
            accA[6][0] = fmaf(a, wb0.z, accA[6][0]); accA[6][1] = fmaf(a, wb1.z, accA[6][1]);
            accA[7][0] = fmaf(a, wb0.w, accA[7][0]); accA[7][1] = fmaf(a, wb1.w, accA[7][1]);
        }
        __syncthreads();
    }
    // ---- k-pair 1 ----
    {
        const float4* W4 = (const float4*)(W + 2 * 4096);   // k2,k3 slices
        float4* sW4 = (float4*)sW;
#pragma unroll
        for (int i = 0; i < 8; ++i) sW4[t + 256 * i] = W4[t + 256 * i];
        __syncthreads();
        for (int d = 0; d < 64; ++d) {
            float a = sh[nl * 65 + d];
            const float4* w0 = (const float4*)&sW[d * 64 + j0];
            const float4* w1 = (const float4*)&sW[4096 + d * 64 + j0];
            float4 wa0 = w0[0], wb0 = w0[1];
            float4 wa1 = w1[0], wb1 = w1[1];
            accB[0][0] = fmaf(a, wa0.x, accB[0][0]); accB[0][1] = fmaf(a, wa1.x, accB[0][1]);
            accB[1][0] = fmaf(a, wa0.y, accB[1][0]); accB[1][1] = fmaf(a, wa1.y, accB[1][1]);
            accB[2][0] = fmaf(a, wa0.z, accB[2][0]); accB[2][1] = fmaf(a, wa1.z, accB[2][1]);
            accB[3][0] = fmaf(a, wa0.w, accB[3][0]); accB[3][1] = fmaf(a, wa1.w, accB[3][1]);
            accB[4][0] = fmaf(a, wb0.x, accB[4][0]); accB[4][1] = fmaf(a, wb1.x, accB[4][1]);
            accB[5][0] = fmaf(a, wb0.y, accB[5][0]); accB[5][1] = fmaf(a, wb1.y, accB[5][1]);
            accB[6][0] = fmaf(a, wb0.z, accB[6][0]); accB[6][1] = fmaf(a, wb1.z, accB[6][1]);
            accB[7][0] = fmaf(a, wb0.w, accB[7][0]); accB[7][1] = fmaf(a, wb1.w, accB[7][1]);
        }
    }

    int n = n0 + nl;
    if (n < N_NODES) {
        // cols j0..j0+7: jg = cg>>1, jj0 = (cg&1)*8
        int jg = cg >> 1;
        int jj0 = (cg & 1) * 8;
        unsigned base = (unsigned)((size_t)0) ;
        unsigned* yb = y + (size_t)n * 128 + jg * 32 + jj0 * 2;
        // col c -> 2 unsigneds: pack2(k0,k1), pack2(k2,k3)
        uint4 o0 = make_uint4(pack2(accA[0][0], accA[0][1]), pack2(accB[0][0], accB[0][1]),
                              pack2(accA[1][0], accA[1][1]), pack2(accB[1][0], accB[1][1]));
        uint4 o1 = make_uint4(pack2(accA[2][0], accA[2][1]), pack2(accB[2][0], accB[2][1]),
                              pack2(accA[3][0], accA[3][1]), pack2(accB[3][0], accB[3][1]));
        uint4 o2 = make_uint4(pack2(accA[4][0], accA[4][1]), pack2(accB[4][0], accB[4][1]),
                              pack2(accA[5][0], accA[5][1]), pack2(accB[5][0], accB[5][1]));
        uint4 o3 = make_uint4(pack2(accA[6][0], accA[6][1]), pack2(accB[6][0], accB[6][1]),
                              pack2(accA[7][0], accA[7][1]), pack2(accB[7][0], accB[7][1]));
        uint4* o = (uint4*)yb;
        o[0] = o0; o[1] = o1; o[2] = o2; o[3] = o3;
        (void)base;
    }
}

// ---- sharded aggregate: block = 16 nodes x ONE col-shard (jg = blockIdx%4) ----
// lane owns one output col; per edge reads uint2 = y[s, jg, lane, k0..3]
__device__ inline float agg_shard(const uint4* __restrict__ rec,
                                  int s0, int deg,
                                  const unsigned* __restrict__ y,
                                  float bias, int jg, int lane) {
    int s1 = s0 + deg;
    const unsigned* yb = y + jg * 32 + lane * 2;
    float acc = 0.f;
    int i = s0;
    for (; i + 4 <= s1; i += 4) {
        uint4 r0 = ldnt4(&rec[i + 0]);
        uint4 r1 = ldnt4(&rec[i + 1]);
        uint4 r2 = ldnt4(&rec[i + 2]);
        uint4 r3 = ldnt4(&rec[i + 3]);
        uint2 q0 = *(const uint2*)(yb + (size_t)r0.x * 128);
        uint2 q1 = *(const uint2*)(yb + (size_t)r1.x * 128);
        uint2 q2 = *(const uint2*)(yb + (size_t)r2.x * 128);
        uint2 q3 = *(const uint2*)(yb + (size_t)r3.x * 128);
#pragma unroll
        for (int u = 0; u < 4; ++u) {
            uint4 r = (u == 0) ? r0 : (u == 1) ? r1 : (u == 2) ? r2 : r3;
            uint2 q = (u == 0) ? q0 : (u == 1) ? q1 : (u == 2) ? q2 : q3;
            float2 e01 = unpack2(r.y);
            float2 e23 = unpack2(r.z);
            float2 v01 = unpack2(q.x);
            float2 v23 = unpack2(q.y);
            float z = bias;
            z = fmaf(e01.x, v01.x, z);
            z = fmaf(e01.y, v01.y, z);
            z = fmaf(e23.x, v23.x, z);
            z = fmaf(e23.y, v23.y, z);
            acc += fmaxf(z, 0.f);
        }
    }
    for (; i < s1; ++i) {
        uint4 r = ldnt4(&rec[i]);
        uint2 q = *(const uint2*)(yb + (size_t)r.x * 128);
        float2 e01 = unpack2(r.y);
        float2 e23 = unpack2(r.z);
        float2 v01 = unpack2(q.x);
        float2 v23 = unpack2(q.y);
        float z = bias;
        z = fmaf(e01.x, v01.x, z);
        z = fmaf(e01.y, v01.y, z);
        z = fmaf(e23.x, v23.x, z);
        z = fmaf(e23.y, v23.y, z);
        acc += fmaxf(z, 0.f);
    }
    float inv = 1.0f / (float)(deg > 1 ? deg : 1);
    return fmaxf(acc * inv, 0.f);
}

// grid: 12500 blocks; shard = blockIdx%4 (XCD-affine under %8 round-robin),
// node-block = blockIdx/4.  16 groups x 16 lanes.
__global__ __launch_bounds__(256) void agg_k(const uint4* __restrict__ rec,
                                             const int* __restrict__ start,
                                             const int* __restrict__ cnt,
                                             const unsigned* __restrict__ y,
                                             const float* __restrict__ b,
                                             float* __restrict__ hout) {
    int jg = blockIdx.x & 3;
    int nb = blockIdx.x >> 2;
    int t = threadIdx.x;
    int g = nb * 16 + (t >> 4);
    int lane = t & 15;
    float bias = b[jg * 16 + lane];
    float r = agg_shard(rec, start[g], cnt[g], y, bias, jg, lane);
    hout[(size_t)g * 64 + jg * 16 + lane] = r;
}

// ---- final fc: out = h @ Wfc + bfc  (streaming, 16 nodes/block) ----
__global__ __launch_bounds__(256) void fc_k(const float* __restrict__ hbuf,
                                            const float* __restrict__ Wfc,
                                            const float* __restrict__ bfc,
                                            float* __restrict__ out) {
    __shared__ float sh_h[16 * 65];
    __shared__ float sWfcT[NCLS * 65];   // transposed, padded
    __shared__ float sbfc[NCLS];
    int t = threadIdx.x;

    for (int i = t; i < 64 * NCLS; i += 256) {
        int j = i / NCLS;
        int c = i - j * NCLS;
        sWfcT[c * 65 + j] = Wfc[i];
    }
    if (t < NCLS) sbfc[t] = bfc[t];

    // stage 16 h rows (grid exact: 3125*16 = 50000)
    int nl = t >> 4;
    int dg = t & 15;
    float4 v = ((const float4*)hbuf)[(size_t)(blockIdx.x * 16 + nl) * 16 + dg];
    sh_h[nl * 65 + dg * 4 + 0] = v.x;
    sh_h[nl * 65 + dg * 4 + 1] = v.y;
    sh_h[nl * 65 + dg * 4 + 2] = v.z;
    sh_h[nl * 65 + dg * 4 + 3] = v.w;
    __syncthreads();

    for (int item = t; item < 16 * NCLS; item += 256) {
        int rn = item / NCLS;
        int c = item - rn * NCLS;
        float acc = sbfc[c];
        const float* hr = &sh_h[rn * 65];
        const float* wc = &sWfcT[c * 65];
#pragma unroll
        for (int j = 0; j < 64; ++j) acc = fmaf(hr[j], wc[j], acc);
        out[(size_t)(blockIdx.x * 16 + rn) * NCLS + c] = acc;
    }
}

extern "C" void kernel_launch(void* const* d_in, const int* in_sizes, int n_in,
                              void* d_out, int out_size, void* d_ws, size_t ws_size,
                              hipStream_t stream) {
    const float* nf  = (const float*)d_in[0];
    const float* ef  = (const float*)d_in[1];
    const int*   src = (const int*)d_in[2];
    const int*   dst = (const int*)d_in[3];
    const float* W0  = (const float*)d_in[4];
    const float* b0  = (const float*)d_in[5];
    const float* W1  = (const float*)d_in[6];
    const float* b1  = (const float*)d_in[7];
    const float* Wfc = (const float*)d_in[8];
    const float* bfc = (const float*)d_in[9];
    float* out = (float*)d_out;

    char* ws = (char*)d_ws;
    size_t off = 0;
    auto alloc = [&](size_t bytes) -> void* {
        void* p = ws + off;
        off = (off + bytes + 255) & ~(size_t)255;
        return p;
    };
    int*      zbuf   = (int*)     alloc((size_t)(50176 + 512) * 4);
    int*      cnt    = zbuf;
    int*      bflag  = zbuf + 50176;
    int*      bval   = zbuf + 50176 + 256;
    int*      start  = (int*)     alloc((size_t)(N_NODES + 1) * 4);
    int*      cursor = (int*)     alloc((size_t)N_NODES * 4);
    uint4*    recA   = (uint4*)   alloc((size_t)N_EDGES * 16);
    uint4*    recB   = (uint4*)   alloc((size_t)N_EDGES * 16);
    unsigned* y      = (unsigned*)alloc((size_t)N_NODES * 256 * 2);
    float*    hbuf   = (float*)   alloc((size_t)N_NODES * 64 * 4);
    float*    hbuf2  = (float*)   alloc((size_t)N_NODES * 64 * 4);

    hipMemsetAsync(zbuf, 0, (size_t)(50176 + 512) * 4, stream);

    hist_k<<<EBLK, 256, 0, stream>>>(dst, cnt);
    scan_k<<<NBLK, 256, 0, stream>>>(cnt, start, cursor, bflag, bval);
    scatter_k<<<EBLK, 256, 0, stream>>>(src, dst, ef, cursor, recA);
    repack_k<<<EBLK, 256, 0, stream>>>(recA, ef + (size_t)N_EDGES * 4, recB);

    int agrid = (N_NODES / 16) * 4;       // 12500: node-blocks x 4 col-shards

    // layer 0
    transform_k<<<TBLK, 256, 0, stream>>>(nf, W0, y);
    agg_k<<<agrid, 256, 0, stream>>>(recA, start, cnt, y, b0, hbuf);

    // layer 1
    transform_k<<<TBLK, 256, 0, stream>>>(hbuf, W1, y);
    agg_k<<<agrid, 256, 0, stream>>>(recB, start, cnt, y, b1, hbuf2);

    // classifier
    fc_k<<<N_NODES / 16, 256, 0, stream>>>(hbuf2, Wfc, bfc, out);
}

// Round 10
// 330.858 us; speedup vs baseline: 1.2774x; 1.2774x over previous
//
#include <hip/hip_runtime.h>
#include <hip/hip_fp16.h>

#define N_NODES 50000
#define N_EDGES 500000
#define DIM 64
#define KDIM 4
#define HID 64
#define NCLS 40
#define NBLK ((N_NODES + 255) / 256)   // 196
#define EBLK ((N_EDGES + 255) / 256)   // 1954

typedef unsigned uv4 __attribute__((ext_vector_type(4)));

__device__ inline unsigned pack2(float a, float b) {
    __half2 h = __floats2half2_rn(a, b);
    return *(unsigned*)&h;
}
__device__ inline float2 unpack2(unsigned u) {
    __half2 h = *(__half2*)&u;
    return __half22float2(h);
}
__device__ inline uint4 ldnt4(const uint4* p) {
    uv4 v = __builtin_nontemporal_load((const uv4*)p);
    return make_uint4(v.x, v.y, v.z, v.w);
}
__device__ inline void stnt4(uint4* p, uint4 v) {
    uv4 w = {v.x, v.y, v.z, v.w};
    __builtin_nontemporal_store(w, (uv4*)p);
}

// ---- histogram of dst (in-degree) ----
__global__ void hist_k(const int* __restrict__ dst, int* __restrict__ cnt) {
    int e = blockIdx.x * 256 + threadIdx.x;
    if (e < N_EDGES) atomicAdd(&cnt[dst[e]], 1);
}

// ---- single-kernel scan: per-block scan + publish + parallel lookback ----
__global__ __launch_bounds__(256) void scan_k(const int* __restrict__ cnt,
                                              int* __restrict__ start,
                                              int* __restrict__ cursor,
                                              volatile int* __restrict__ bflag,
                                              volatile int* __restrict__ bval) {
    __shared__ int ls[256];
    __shared__ int sbase;
    __shared__ int ok_all;
    int b = blockIdx.x, t = threadIdx.x;
    int n = b * 256 + t;
    int v = (n < N_NODES) ? cnt[n] : 0;
    ls[t] = v;
    __syncthreads();
#pragma unroll
    for (int off = 1; off < 256; off <<= 1) {
        int u = (t >= off) ? ls[t - off] : 0;
        __syncthreads();
        ls[t] += u;
        __syncthreads();
    }
    int incl = ls[t];
    int total = ls[255];
    __syncthreads();

    if (t == 0) {
        bval[b] = total;
        __threadfence();
        bflag[b] = 1;
    }

    if (b > 0) {
        for (;;) {
            int f = (t < b) ? bflag[t] : 1;
            if (t == 0) ok_all = 1;
            __syncthreads();
            if (!f) ok_all = 0;
            __syncthreads();
            if (ok_all) break;
        }
        __threadfence();
        int pv = (t < b) ? bval[t] : 0;
        ls[t] = pv;
        __syncthreads();
#pragma unroll
        for (int off = 128; off > 0; off >>= 1) {
            if (t < off) ls[t] += ls[t + off];
            __syncthreads();
        }
        if (t == 0) sbase = ls[0];
        __syncthreads();
    } else {
        if (t == 0) sbase = 0;
        __syncthreads();
    }

    int excl = sbase + incl - v;
    if (n < N_NODES) { start[n] = excl; cursor[n] = excl; }
    if (n == 0) start[N_NODES] = N_EDGES;
}

// ---- counting-sort scatter: ONE interleaved 32B record pair per edge ----
__global__ void scatter_k(const int* __restrict__ src, const int* __restrict__ dst,
                          const float* __restrict__ ef, int* __restrict__ cursor,
                          uint4* __restrict__ rec) {
    int e = blockIdx.x * 256 + threadIdx.x;
    if (e < N_EDGES) {
        int d = dst[e];
        int pos = atomicAdd(&cursor[d], 1);
        int sn = src[e];
        float4 f0 = ((const float4*)ef)[e];
        float4 f1 = ((const float4*)ef)[N_EDGES + e];
        stnt4(&rec[2 * pos],     make_uint4((unsigned)sn, pack2(f0.x, f0.y), pack2(f0.z, f0.w), 0u));
        stnt4(&rec[2 * pos + 1], make_uint4((unsigned)sn, pack2(f1.x, f1.y), pack2(f1.z, f1.w), 0u));
    }
}

// ---- node transform, split-k pair: blockIdx.y = kp (k in {2kp, 2kp+1}) ----
// y row layout (128 unsigned): idx = blk*64 + lane*4 + kp*2 + cp
//   where col c = blk*32 + 2*lane + cp; unsigned = pack2(val[c][2kp], val[c][2kp+1])
// -> agg lane reads 2x uint4 (256B wave segments) covering cols {2l,2l+1,32+2l,33+2l} x all k
// 64 nodes/block, 32KB W-slice + 16.6KB h-tile -> 3 blocks/CU (round-4 proven shape)
__global__ __launch_bounds__(256) void transform_k(const float* __restrict__ hin,
                                                   const float* __restrict__ W,
                                                   unsigned* __restrict__ y) {
    __shared__ float sW[2 * 64 * 64];      // 32 KB: the kpair's two k-slices
    __shared__ float sh[64 * 65];          // 16.6 KB
    int t = threadIdx.x;
    int kp = blockIdx.y;

    const float4* W4 = (const float4*)(W + (size_t)kp * 2 * 4096);
    float4* sW4 = (float4*)sW;
#pragma unroll
    for (int i = 0; i < 8; ++i) sW4[t + 256 * i] = W4[t + 256 * i];

    int n0 = blockIdx.x * 64;
#pragma unroll
    for (int i = 0; i < 4; ++i) {
        int idx = t + 256 * i;        // 0..1023
        int nl = idx >> 4;            // 0..63
        int dg = idx & 15;
        int n = n0 + nl;
        float4 v = make_float4(0.f, 0.f, 0.f, 0.f);
        if (n < N_NODES) v = ((const float4*)hin)[(size_t)n * 16 + dg];
        sh[nl * 65 + dg * 4 + 0] = v.x;
        sh[nl * 65 + dg * 4 + 1] = v.y;
        sh[nl * 65 + dg * 4 + 2] = v.z;
        sh[nl * 65 + dg * 4 + 3] = v.w;
    }
    __syncthreads();

    // 256 threads = 8 col-groups (8 cols x BOTH k of the pair) x 32 node-slots
    int nl = t & 31;
    int cg = t >> 5;                  // 0..7
    int j0 = cg * 8;

    float a0c[8][2], a1c[8][2];       // [col][k_local]
#pragma unroll
    for (int c = 0; c < 8; ++c) {
        a0c[c][0] = 0.f; a0c[c][1] = 0.f;
        a1c[c][0] = 0.f; a1c[c][1] = 0.f;
    }

    for (int d = 0; d < 64; ++d) {
        float a0 = sh[nl * 65 + d];
        float a1 = sh[(nl + 32) * 65 + d];
        const float4* wl = (const float4*)&sW[d * 64 + j0];          // k_lo slice
        const float4* wh = (const float4*)&sW[4096 + d * 64 + j0];   // k_hi slice
        float4 wl0 = wl[0], wl1 = wl[1];
        float4 wh0 = wh[0], wh1 = wh[1];
        float wlv[8] = {wl0.x, wl0.y, wl0.z, wl0.w, wl1.x, wl1.y, wl1.z, wl1.w};
        float whv[8] = {wh0.x, wh0.y, wh0.z, wh0.w, wh1.x, wh1.y, wh1.z, wh1.w};
#pragma unroll
        for (int c = 0; c < 8; ++c) {
            a0c[c][0] = fmaf(a0, wlv[c], a0c[c][0]);
            a0c[c][1] = fmaf(a0, whv[c], a0c[c][1]);
            a1c[c][0] = fmaf(a1, wlv[c], a1c[c][0]);
            a1c[c][1] = fmaf(a1, whv[c], a1c[c][1]);
        }
    }

    int blk = cg >> 2;                // cols 0-31 vs 32-63
    int l0 = (cg & 3) * 4;            // first lane slot covered by this thread
    int nA = n0 + nl, nB = n0 + nl + 32;
    if (nA < N_NODES) {
        unsigned* yb = y + (size_t)nA * 128 + blk * 64 + kp * 2;
#pragma unroll
        for (int i2 = 0; i2 < 4; ++i2) {
            uint2 v2 = make_uint2(pack2(a0c[2 * i2][0],     a0c[2 * i2][1]),
                                  pack2(a0c[2 * i2 + 1][0], a0c[2 * i2 + 1][1]));
            *(uint2*)(yb + (l0 + i2) * 4) = v2;
        }
    }
    if (nB < N_NODES) {
        unsigned* yb = y + (size_t)nB * 128 + blk * 64 + kp * 2;
#pragma unroll
        for (int i2 = 0; i2 < 4; ++i2) {
            uint2 v2 = make_uint2(pack2(a1c[2 * i2][0],     a1c[2 * i2][1]),
                                  pack2(a1c[2 * i2 + 1][0], a1c[2 * i2 + 1][1]));
            *(uint2*)(yb + (l0 + i2) * 4) = v2;
        }
    }
}

// ---- edge load/compute: lane reads 2x uint4 (2x 256B wave segments per edge) ----
__device__ inline void load_edge(const uint4 r, const unsigned* __restrict__ y,
                                 int lane, uint4& qlo, uint4& qhi) {
    const uint4* yb = (const uint4*)(y + (size_t)r.x * 128);
    qlo = yb[lane];        // cols 2l,2l+1   (all 4 k)
    qhi = yb[16 + lane];   // cols 32+2l,33+2l
}

__device__ inline void compute_edge(const uint4 r, uint4 qlo, uint4 qhi,
                                    const float4 bias, float4& acc) {
    float2 e01 = unpack2(r.y);
    float2 e23 = unpack2(r.z);
    float2 p, q;
    float z;
    // col 2l:    qlo.x = (k0,k1), qlo.z = (k2,k3)
    p = unpack2(qlo.x); q = unpack2(qlo.z);
    z = bias.x;
    z = fmaf(e01.x, p.x, z); z = fmaf(e01.y, p.y, z);
    z = fmaf(e23.x, q.x, z); z = fmaf(e23.y, q.y, z);
    acc.x += fmaxf(z, 0.f);
    // col 2l+1:  qlo.y, qlo.w
    p = unpack2(qlo.y); q = unpack2(qlo.w);
    z = bias.y;
    z = fmaf(e01.x, p.x, z); z = fmaf(e01.y, p.y, z);
    z = fmaf(e23.x, q.x, z); z = fmaf(e23.y, q.y, z);
    acc.y += fmaxf(z, 0.f);
    // col 32+2l: qhi.x, qhi.z
    p = unpack2(qhi.x); q = unpack2(qhi.z);
    z = bias.z;
    z = fmaf(e01.x, p.x, z); z = fmaf(e01.y, p.y, z);
    z = fmaf(e23.x, q.x, z); z = fmaf(e23.y, q.y, z);
    acc.z += fmaxf(z, 0.f);
    // col 33+2l: qhi.y, qhi.w
    p = unpack2(qhi.y); q = unpack2(qhi.w);
    z = bias.w;
    z = fmaf(e01.x, p.x, z); z = fmaf(e01.y, p.y, z);
    z = fmaf(e23.x, q.x, z); z = fmaf(e23.y, q.y, z);
    acc.w += fmaxf(z, 0.f);
}

// ---- aggregate core: unroll-4 over interleaved records (stride 2) ----
__device__ inline float4 agg_core(const uint4* __restrict__ rec2,
                                  const int* __restrict__ start,
                                  const int* __restrict__ cnt,
                                  const unsigned* __restrict__ y,
                                  const float* __restrict__ b,
                                  int g, int lane) {
    int s0 = start[g];
    int deg = cnt[g];
    int s1 = s0 + deg;

    float2 blo = ((const float2*)b)[lane];
    float2 bhi = ((const float2*)b)[16 + lane];
    float4 bias = make_float4(blo.x, blo.y, bhi.x, bhi.y);
    float4 acc = make_float4(0.f, 0.f, 0.f, 0.f);

    int i = s0;
    for (; i + 4 <= s1; i += 4) {
        uint4 r0 = ldnt4(&rec2[2 * i + 0]);
        uint4 r1 = ldnt4(&rec2[2 * i + 2]);
        uint4 r2 = ldnt4(&rec2[2 * i + 4]);
        uint4 r3 = ldnt4(&rec2[2 * i + 6]);
        uint4 aL, aH, bL, bH, cL, cH, dL, dH;
        load_edge(r0, y, lane, aL, aH);
        load_edge(r1, y, lane, bL, bH);
        load_edge(r2, y, lane, cL, cH);
        load_edge(r3, y, lane, dL, dH);
        compute_edge(r0, aL, aH, bias, acc);
        compute_edge(r1, bL, bH, bias, acc);
        compute_edge(r2, cL, cH, bias, acc);
        compute_edge(r3, dL, dH, bias, acc);
    }
    if (i + 2 <= s1) {
        uint4 r0 = ldnt4(&rec2[2 * i + 0]);
        uint4 r1 = ldnt4(&rec2[2 * i + 2]);
        uint4 aL, aH, bL, bH;
        load_edge(r0, y, lane, aL, aH);
        load_edge(r1, y, lane, bL, bH);
        compute_edge(r0, aL, aH, bias, acc);
        compute_edge(r1, bL, bH, bias, acc);
        i += 2;
    }
    if (i < s1) {
        uint4 r0 = ldnt4(&rec2[2 * i]);
        uint4 aL, aH;
        load_edge(r0, y, lane, aL, aH);
        compute_edge(r0, aL, aH, bias, acc);
    }

    float inv = 1.0f / (float)(deg > 1 ? deg : 1);
    float4 r;
    r.x = fmaxf(acc.x * inv, 0.f);
    r.y = fmaxf(acc.y * inv, 0.f);
    r.z = fmaxf(acc.z * inv, 0.f);
    r.w = fmaxf(acc.w * inv, 0.f);
    return r;
}

// ---- layer-0 aggregate ----
__global__ __launch_bounds__(256) void agg_k(const uint4* __restrict__ rec2,
                                             const int* __restrict__ start,
                                             const int* __restrict__ cnt,
                                             const unsigned* __restrict__ y,
                                             const float* __restrict__ b,
                                             float* __restrict__ hout) {
    int t = blockIdx.x * 256 + threadIdx.x;
    int g = t >> 4;
    int lane = t & 15;
    float4 r = agg_core(rec2, start, cnt, y, b, g, lane);
    float2* o = (float2*)(hout + (size_t)g * 64);
    o[lane]      = make_float2(r.x, r.y);   // cols 2l, 2l+1
    o[16 + lane] = make_float2(r.z, r.w);   // cols 32+2l, 33+2l
}

// ---- layer-1 aggregate fused with final fc (block = 16 nodes) ----
__global__ __launch_bounds__(256) void agg_fc_k(const uint4* __restrict__ rec2,
                                                const int* __restrict__ start,
                                                const int* __restrict__ cnt,
                                                const unsigned* __restrict__ y,
                                                const float* __restrict__ b,
                                                const float* __restrict__ Wfc,
                                                const float* __restrict__ bfc,
                                                float* __restrict__ out) {
    __shared__ float sh_h[16 * 65];
    __shared__ float sWfcT[NCLS * 65];   // transposed, padded: [c*65 + j]
    __shared__ float sbfc[NCLS];
    int t = threadIdx.x;

    for (int i = t; i < 64 * NCLS; i += 256) {
        int j = i / NCLS;
        int c = i - j * NCLS;
        sWfcT[c * 65 + j] = Wfc[i];
    }
    if (t < NCLS) sbfc[t] = bfc[t];

    int nl = t >> 4;
    int lane = t & 15;
    int g = blockIdx.x * 16 + nl;   // grid exact: 3125*16 = 50000

    float4 r = agg_core(rec2, start, cnt, y, b, g, lane);
    sh_h[nl * 65 + 2 * lane]      = r.x;
    sh_h[nl * 65 + 2 * lane + 1]  = r.y;
    sh_h[nl * 65 + 32 + 2 * lane] = r.z;
    sh_h[nl * 65 + 33 + 2 * lane] = r.w;
    __syncthreads();

    for (int item = t; item < 16 * NCLS; item += 256) {
        int rn = item / NCLS;
        int c = item - rn * NCLS;
        float acc = sbfc[c];
        const float* hr = &sh_h[rn * 65];
        const float* wc = &sWfcT[c * 65];
#pragma unroll
        for (int j = 0; j < 64; ++j) acc = fmaf(hr[j], wc[j], acc);
        out[(size_t)(blockIdx.x * 16 + rn) * NCLS + c] = acc;
    }
}

extern "C" void kernel_launch(void* const* d_in, const int* in_sizes, int n_in,
                              void* d_out, int out_size, void* d_ws, size_t ws_size,
                              hipStream_t stream) {
    const float* nf  = (const float*)d_in[0];
    const float* ef  = (const float*)d_in[1];
    const int*   src = (const int*)d_in[2];
    const int*   dst = (const int*)d_in[3];
    const float* W0  = (const float*)d_in[4];
    const float* b0  = (const float*)d_in[5];
    const float* W1  = (const float*)d_in[6];
    const float* b1  = (const float*)d_in[7];
    const float* Wfc = (const float*)d_in[8];
    const float* bfc = (const float*)d_in[9];
    float* out = (float*)d_out;

    char* ws = (char*)d_ws;
    size_t off = 0;
    auto alloc = [&](size_t bytes) -> void* {
        void* p = ws + off;
        off = (off + bytes + 255) & ~(size_t)255;
        return p;
    };
    int*      zbuf   = (int*)     alloc((size_t)(50176 + 512) * 4);
    int*      cnt    = zbuf;
    int*      bflag  = zbuf + 50176;
    int*      bval   = zbuf + 50176 + 256;
    int*      start  = (int*)     alloc((size_t)(N_NODES + 1) * 4);
    int*      cursor = (int*)     alloc((size_t)N_NODES * 4);
    uint4*    rec    = (uint4*)   alloc((size_t)N_EDGES * 32);
    unsigned* y      = (unsigned*)alloc((size_t)N_NODES * 256 * 2);
    float*    hbuf   = (float*)   alloc((size_t)N_NODES * 64 * 4);

    hipMemsetAsync(zbuf, 0, (size_t)(50176 + 512) * 4, stream);

    hist_k<<<EBLK, 256, 0, stream>>>(dst, cnt);
    scan_k<<<NBLK, 256, 0, stream>>>(cnt, start, cursor, bflag, bval);
    scatter_k<<<EBLK, 256, 0, stream>>>(src, dst, ef, cursor, rec);

    dim3 tgrid((N_NODES + 63) / 64, 2);   // 782 x 2 (split k-pair)
    int agrid = N_NODES / 16;             // 3125, exact

    // layer 0
    transform_k<<<tgrid, 256, 0, stream>>>(nf, W0, y);
    agg_k<<<agrid, 256, 0, stream>>>(rec, start, cnt, y, b0, hbuf);

    // layer 1 + fused classifier
    transform_k<<<tgrid, 256, 0, stream>>>(hbuf, W1, y);
    agg_fc_k<<<agrid, 256, 0, stream>>>(rec + 1, start, cnt, y, b1, Wfc, bfc, out);
}